// Round 1
// baseline (24.635 us; speedup 1.0000x reference)
//
#include <hip/hip_runtime.h>
#include <hip/hip_bf16.h>

// BoundaryLoss: loss[n,c] = sum_{h,w} softmax[n,c,h,w] * dist[n,c,h,w], c in 1..C-1
// output = mean over (n, c>0)  ->  single fp32 scalar.
// N=16, C=4, H=W=512. Elements per class-plane = 512*512 = 262144.
// Per n: skip class 0 plane, read classes 1..3 (contiguous chunk).

#define NB 16
#define CB 4
#define PLANE 262144            // H*W
#define PLANE4 (PLANE / 4)      // 65536 float4 per plane
#define PERN4 (3 * PLANE4)      // 196608 float4 of classes 1..3 per n
#define STRIDEN4 (CB * PLANE4)  // 262144 float4 per n (full)
#define TOTAL4 (NB * PERN4)     // 3145728 float4 pairs total

#define BLOCKS 2048
#define THREADS 256

__global__ __launch_bounds__(THREADS) void bl_pass1(const float4* __restrict__ sm,
                                                    const float4* __restrict__ dm,
                                                    float* __restrict__ partial) {
    float acc = 0.0f;
    for (int idx = blockIdx.x * THREADS + threadIdx.x; idx < TOTAL4;
         idx += BLOCKS * THREADS) {
        int n = idx / PERN4;
        int r = idx - n * PERN4;
        int off = n * STRIDEN4 + PLANE4 + r;  // skip class-0 plane
        float4 a = sm[off];
        float4 b = dm[off];
        acc += a.x * b.x + a.y * b.y + a.z * b.z + a.w * b.w;
    }
    // wave64 reduce
    #pragma unroll
    for (int o = 32; o >= 1; o >>= 1) acc += __shfl_down(acc, o, 64);
    __shared__ float s[THREADS / 64];
    int lane = threadIdx.x & 63;
    int wid = threadIdx.x >> 6;
    if (lane == 0) s[wid] = acc;
    __syncthreads();
    if (threadIdx.x == 0) {
        float t = 0.0f;
        #pragma unroll
        for (int i = 0; i < THREADS / 64; ++i) t += s[i];
        partial[blockIdx.x] = t;
    }
}

__global__ __launch_bounds__(THREADS) void bl_pass2(const float* __restrict__ partial,
                                                    float* __restrict__ out) {
    float acc = 0.0f;
    for (int i = threadIdx.x; i < BLOCKS; i += THREADS) acc += partial[i];
    #pragma unroll
    for (int o = 32; o >= 1; o >>= 1) acc += __shfl_down(acc, o, 64);
    __shared__ float s[THREADS / 64];
    int lane = threadIdx.x & 63;
    int wid = threadIdx.x >> 6;
    if (lane == 0) s[wid] = acc;
    __syncthreads();
    if (threadIdx.x == 0) {
        float t = 0.0f;
        #pragma unroll
        for (int i = 0; i < THREADS / 64; ++i) t += s[i];
        out[0] = t * (1.0f / 48.0f);  // mean over N*(C-1) = 48
    }
}

extern "C" void kernel_launch(void* const* d_in, const int* in_sizes, int n_in,
                              void* d_out, int out_size, void* d_ws, size_t ws_size,
                              hipStream_t stream) {
    const float4* sm = (const float4*)d_in[0];  // softmax_output, fp32 NCHW
    // d_in[1] = target (int32) -- unused on the precomputed-distance-map path
    const float4* dm = (const float4*)d_in[2];  // distance_maps, fp32 NCHW
    float* out = (float*)d_out;
    float* partial = (float*)d_ws;  // BLOCKS floats, well under ws_size

    bl_pass1<<<BLOCKS, THREADS, 0, stream>>>(sm, dm, partial);
    bl_pass2<<<1, THREADS, 0, stream>>>(partial, out);
}